// Round 2
// baseline (1104.630 us; speedup 1.0000x reference)
//
#include <hip/hip_runtime.h>

#define T_LEN 2048
#define HID   25
#define LOG2E 1.4426950408889634f

__device__ __forceinline__ float fast_rcp(float x) { return __builtin_amdgcn_rcpf(x); }
__device__ __forceinline__ float fast_exp2(float x) { return __builtin_amdgcn_exp2f(x); }

// sigmoid(x) = rcp(1 + exp2(-x*log2e)); tanh(x) = 1 - 2*rcp(1 + exp2(2x*log2e))
// Weights/biases are pre-scaled by -log2e (i,f,o) or +2log2e (g) so the hot loop
// needs only v_exp_f32 + v_rcp_f32 per gate.

__global__ __launch_bounds__(256, 1) void lstm_fused(
    const float* __restrict__ x,        // [B, T, 1]
    const float* __restrict__ w_ih,     // [100, 1]
    const float* __restrict__ w_hh,     // [100, 25]
    const float* __restrict__ b_ih,     // [100]
    const float* __restrict__ b_hh,     // [100]
    const float* __restrict__ w_dense,  // [1, 25]
    const float* __restrict__ b_dense,  // [1]
    float* __restrict__ out)            // [B, T, 1]
{
    const int tid    = threadIdx.x;
    const int lane32 = tid & 31;
    const int cl     = tid >> 5;                    // chain-local index, 0..7 (one per 32-lane half)
    const int b      = blockIdx.x * 8 + cl;         // batch/chain index
    const int j      = lane32;                      // hidden unit owned by this lane
    const bool act   = (j < HID);

    // h exchange buffer: 32 floats (128 B) per chain. The two 32-lane halves of a
    // wave broadcast-read from rows 128 B apart -> 2-way bank alias, which is free.
    __shared__ __align__(16) float hbuf[8][32];

    const float si = -LOG2E, sf = -LOG2E, sg = 2.0f * LOG2E, so = -LOG2E;
    const int ri = j, rf = HID + j, rg = 2 * HID + j, ro = 3 * HID + j;

    // ---- recurrent weights, fp32, pre-scaled into exp2 domain (100 VGPRs) ----
    float wI[HID], wF[HID], wG[HID], wO[HID];
#pragma unroll
    for (int k = 0; k < HID; ++k) {
        wI[k] = act ? si * w_hh[ri * HID + k] : 0.f;
        wF[k] = act ? sf * w_hh[rf * HID + k] : 0.f;
        wG[k] = act ? sg * w_hh[rg * HID + k] : 0.f;
        wO[k] = act ? so * w_hh[ro * HID + k] : 0.f;
    }
    const float bi = act ? si * (b_ih[ri] + b_hh[ri]) : 0.f;
    const float bf = act ? sf * (b_ih[rf] + b_hh[rf]) : 0.f;
    const float bg = act ? sg * (b_ih[rg] + b_hh[rg]) : 0.f;
    const float bo = act ? so * (b_ih[ro] + b_hh[ro]) : 0.f;
    const float wxi = act ? si * w_ih[ri] : 0.f;
    const float wxf = act ? sf * w_ih[rf] : 0.f;
    const float wxg = act ? sg * w_ih[rg] : 0.f;
    const float wxo = act ? so * w_ih[ro] : 0.f;
    const float wd = act ? w_dense[j] : 0.f;
    const float bd = b_dense[0];

    const float4* __restrict__ xp = (const float4*)(x + (size_t)b * T_LEN);
    float* __restrict__ orow = out + (size_t)b * T_LEN;
    const float4* __restrict__ hb4 = (const float4*)&hbuf[cl][0];
    const float* __restrict__ hbF = (const float*)&hbuf[cl][0];
    float* __restrict__ hwr = &hbuf[cl][j];

    // full h vector held per-lane (read back from LDS each step); h0 = 0
    float hv[HID];
#pragma unroll
    for (int k = 0; k < HID; ++k) hv[k] = 0.f;

    float c = 0.f;
    float yroll = 0.f;
    float4 xcur = xp[0];

    for (int it = 0; it < T_LEN / 4; ++it) {
        const int nx = (it + 1 < T_LEN / 4) ? it + 1 : it;
        float4 xnext = xp[nx];  // prefetch ~4 steps (~1000 cyc) ahead
        float xs[4] = {xcur.x, xcur.y, xcur.z, xcur.w};

#pragma unroll
        for (int s = 0; s < 4; ++s) {
            const float xv = xs[s];
            const int t = 4 * it + s;

            float ai = fmaf(xv, wxi, bi);
            float af = fmaf(xv, wxf, bf);
            float ag = fmaf(xv, wxg, bg);
            float ao = fmaf(xv, wxo, bo);

#pragma unroll
            for (int k = 0; k < HID; ++k) {
                const float h = hv[k];
                ai = fmaf(h, wI[k], ai);
                af = fmaf(h, wF[k], af);
                ag = fmaf(h, wG[k], ag);
                ao = fmaf(h, wO[k], ao);
            }

            const float ig = fast_rcp(1.f + fast_exp2(ai));
            const float fg = fast_rcp(1.f + fast_exp2(af));
            const float og = fast_rcp(1.f + fast_exp2(ao));
            const float tg = fmaf(-2.f, fast_rcp(1.f + fast_exp2(ag)), 1.f);

            c = fmaf(fg, c, ig * tg);
            const float tc = fmaf(-2.f, fast_rcp(1.f + fast_exp2(2.f * LOG2E * c)), 1.f);
            const float hn = og * tc;

            // publish h_t, then immediately issue next step's broadcast reads so the
            // y-reduction below hides in the LDS latency shadow. Same-wave DS ops are
            // in-order: no barrier needed (both chains of a wave run in lockstep).
            *hwr = hn;
            {
                float4 a0 = hb4[0], a1 = hb4[1], a2 = hb4[2];
                float4 a3 = hb4[3], a4 = hb4[4], a5 = hb4[5];
                hv[0] = a0.x;  hv[1] = a0.y;  hv[2] = a0.z;  hv[3] = a0.w;
                hv[4] = a1.x;  hv[5] = a1.y;  hv[6] = a1.z;  hv[7] = a1.w;
                hv[8] = a2.x;  hv[9] = a2.y;  hv[10] = a2.z; hv[11] = a2.w;
                hv[12] = a3.x; hv[13] = a3.y; hv[14] = a3.z; hv[15] = a3.w;
                hv[16] = a4.x; hv[17] = a4.y; hv[18] = a4.z; hv[19] = a4.w;
                hv[20] = a5.x; hv[21] = a5.y; hv[22] = a5.z; hv[23] = a5.w;
                hv[24] = hbF[24];
            }

            // y_t = sum_j h_j * wd_j (+bd at store); butterfly over the 32-lane half
            float ys = hn * wd;
            ys += __shfl_xor(ys, 16, 32);
            ys += __shfl_xor(ys, 8, 32);
            ys += __shfl_xor(ys, 4, 32);
            ys += __shfl_xor(ys, 2, 32);
            ys += __shfl_xor(ys, 1, 32);
            yroll = ((t & 31) == lane32) ? ys : yroll;

            if ((t & 31) == 31) {
                orow[(t & ~31) + lane32] = yroll + bd;  // coalesced 128 B per chain
            }
        }
        xcur = xnext;
    }
}

extern "C" void kernel_launch(void* const* d_in, const int* in_sizes, int n_in,
                              void* d_out, int out_size, void* d_ws, size_t ws_size,
                              hipStream_t stream) {
    const float* x       = (const float*)d_in[0];
    const float* w_ih    = (const float*)d_in[1];
    const float* w_hh    = (const float*)d_in[2];
    const float* b_ih    = (const float*)d_in[3];
    const float* b_hh    = (const float*)d_in[4];
    const float* w_dense = (const float*)d_in[5];
    const float* b_dense = (const float*)d_in[6];
    float* out = (float*)d_out;

    // 2048 chains, 8 per block (one per 32-lane half-wave) -> 256 blocks,
    // 1024 waves = exactly 1 wave per SIMD across the chip.
    lstm_fused<<<dim3(256), dim3(256), 0, stream>>>(x, w_ih, w_hh, b_ih, b_hh,
                                                    w_dense, b_dense, out);
}

// Round 4
// 793.546 us; speedup vs baseline: 1.3920x; 1.3920x over previous
//
#include <hip/hip_runtime.h>

#define T_LEN 2048
#define HID   25
#define LOG2E 1.4426950408889634f

__device__ __forceinline__ float fast_rcp(float x) { return __builtin_amdgcn_rcpf(x); }
__device__ __forceinline__ float fast_exp2(float x) { return __builtin_amdgcn_exp2f(x); }

// One chain per 64-lane wave. Lower lane u owns gate rows i_u,g_u; upper lane
// 32+u owns f_u,o_u (50 fp32 weights/lane -> no spills). Uniform code on both
// halves; one shfl_xor(32) hands i*tanh(g) to the upper half which owns c,h.
// sigmoid/tanh evaluated in exp2 domain (weights pre-scaled by -log2e / +2log2e)
// -> v_exp_f32 + v_rcp_f32 only. Accumulation order per gate row is the exact
// sequential k=0..24 fma order of the R2 kernel that passed at 1.95e-3.

__global__ __launch_bounds__(256, 2) void lstm_fused(
    const float* __restrict__ x,        // [B, T, 1]
    const float* __restrict__ w_ih,     // [100, 1]
    const float* __restrict__ w_hh,     // [100, 25]
    const float* __restrict__ b_ih,     // [100]
    const float* __restrict__ b_hh,     // [100]
    const float* __restrict__ w_dense,  // [1, 25]
    const float* __restrict__ b_dense,  // [1]
    float* __restrict__ out)            // [B, T, 1]
{
    const int tid  = threadIdx.x;
    const int L    = tid & 63;           // lane in wave
    const int u    = L & 31;             // hidden-unit index this lane serves
    const bool up  = L >= 32;            // upper half: f/o rows, owns c and h
    const int cl   = tid >> 6;           // wave (= chain) index in block, 0..3
    const int b    = blockIdx.x * 4 + cl;
    const bool act = u < HID;

    // Two rows per wave: [2cl+0] = scratch (lower half's junk h-writes land
    // here), [2cl+1] = real h. Publish is unconditional -> no exec-mask dance.
    // Lower/upper lane u write addresses 128 B apart = same bank: a 2-way
    // conflict, which is free on gfx950 (m136).
    __shared__ __align__(16) float hbuf[8][32];

    const int rowA = up ? (HID + u)     : u;              // f-row : i-row
    const int rowB = up ? (3 * HID + u) : (2 * HID + u);  // o-row : g-row
    const float sclA = -LOG2E;                            // sigmoid gates
    const float sclB = up ? -LOG2E : 2.f * LOG2E;         // o: sigmoid, g: tanh

    // ---- 50 recurrent fp32 weights per lane, pre-scaled into exp2 domain ----
    float wAv[HID], wBv[HID];
#pragma unroll
    for (int k = 0; k < HID; ++k) {
        wAv[k] = act ? sclA * w_hh[rowA * HID + k] : 0.f;
        wBv[k] = act ? sclB * w_hh[rowB * HID + k] : 0.f;
    }
    const float bA  = act ? sclA * (b_ih[rowA] + b_hh[rowA]) : 0.f;
    const float bB  = act ? sclB * (b_ih[rowB] + b_hh[rowB]) : 0.f;
    const float wxA = act ? sclA * w_ih[rowA] : 0.f;
    const float wxB = act ? sclB * w_ih[rowB] : 0.f;
    const float wd  = (up && act) ? w_dense[u] : 0.f;     // only upper h is real
    const float bd  = b_dense[0];
    // tB = fmaf(-tmul, sB, 1): tanh(g) on lower half, exactly 1.0 on upper
    const float tmul = up ? 0.f : 2.f;

    // h0 = 0 (also zeroes pad slots 25..31 that later b128 reads touch)
    if (L < 32) { hbuf[2 * cl][L] = 0.f; hbuf[2 * cl + 1][L] = 0.f; }

    // NOTE: deliberately NOT __restrict__ — these alias hbuf and the compiler
    // must keep the publish-before-readback order (R3's failure suspect).
    float* hwr = &hbuf[2 * cl + (up ? 1 : 0)][u];
    const float4* r4 = (const float4*)&hbuf[2 * cl + 1][0];
    const float* hbF = &hbuf[2 * cl + 1][0];

    const float4* __restrict__ xp = (const float4*)(x + (size_t)b * T_LEN);
    float* __restrict__ orow = out + (size_t)b * T_LEN;

    float hv[HID];
#pragma unroll
    for (int k = 0; k < HID; ++k) hv[k] = 0.f;

    float c = 0.f;        // real on upper half, bounded junk on lower
    float yroll = 0.f;
    float4 xcur = xp[0];

    for (int it = 0; it < T_LEN / 4; ++it) {
        const int nx = (it + 1 < T_LEN / 4) ? it + 1 : it;
        float4 xnext = xp[nx];  // prefetch ~4 steps ahead
        float xs[4] = {xcur.x, xcur.y, xcur.z, xcur.w};

#pragma unroll
        for (int s = 0; s < 4; ++s) {
            const float xv = xs[s];
            const int t = 4 * it + s;

            float aA = fmaf(xv, wxA, bA);   // lower: i-preact, upper: f-preact
            float aB = fmaf(xv, wxB, bB);   // lower: g-preact, upper: o-preact
#pragma unroll
            for (int k = 0; k < HID; ++k) {
                const float h = hv[k];
                aA = fmaf(h, wAv[k], aA);
                aB = fmaf(h, wBv[k], aB);
            }

            const float sA = fast_rcp(1.f + fast_exp2(aA));  // sig(i) / sig(f)
            const float sB = fast_rcp(1.f + fast_exp2(aB));  // g-aux  / sig(o)
            const float tB = fmaf(-tmul, sB, 1.f);           // tanh(g) / 1.0
            const float vv = sA * tB;                        // i*tanh(g) / sig(f)
            const float ov = __shfl_xor(vv, 32, 64);         // swap halves

            c = fmaf(vv, c, ov);             // upper: f*c + i*g   (lower: junk)
            const float tC = fmaf(-2.f, fast_rcp(1.f + fast_exp2(2.f * LOG2E * c)), 1.f);
            const float hn = sB * tC;        // upper: o*tanh(c)   (lower: junk)

            // publish h_t (upper -> real row, lower junk -> scratch row), then
            // read it back. Same-wave DS ops execute in order; the asm memory
            // barriers stop the compiler from hoisting reads above the write.
            *hwr = hn;
            __asm__ __volatile__("" ::: "memory");
            {
                float4 a0 = r4[0], a1 = r4[1], a2 = r4[2];
                float4 a3 = r4[3], a4 = r4[4], a5 = r4[5];
                hv[0]  = a0.x; hv[1]  = a0.y; hv[2]  = a0.z; hv[3]  = a0.w;
                hv[4]  = a1.x; hv[5]  = a1.y; hv[6]  = a1.z; hv[7]  = a1.w;
                hv[8]  = a2.x; hv[9]  = a2.y; hv[10] = a2.z; hv[11] = a2.w;
                hv[12] = a3.x; hv[13] = a3.y; hv[14] = a3.z; hv[15] = a3.w;
                hv[16] = a4.x; hv[17] = a4.y; hv[18] = a4.z; hv[19] = a4.w;
                hv[20] = a5.x; hv[21] = a5.y; hv[22] = a5.z; hv[23] = a5.w;
                hv[24] = hbF[24];
            }
            __asm__ __volatile__("" ::: "memory");

            // y_t = sum_u h_u * wd_u; butterfly within the upper 32-lane half
            // (xor masks <32 never cross halves; lower half sums junk*0 = 0)
            float ys = hn * wd;
            ys += __shfl_xor(ys, 16, 64);
            ys += __shfl_xor(ys, 8, 64);
            ys += __shfl_xor(ys, 4, 64);
            ys += __shfl_xor(ys, 2, 64);
            ys += __shfl_xor(ys, 1, 64);
            yroll = ((t & 31) == u) ? ys : yroll;

            if (((t & 31) == 31) && up) {
                orow[(t & ~31) + u] = yroll + bd;   // 128 B coalesced per chain
            }
        }
        xcur = xnext;
    }
}

extern "C" void kernel_launch(void* const* d_in, const int* in_sizes, int n_in,
                              void* d_out, int out_size, void* d_ws, size_t ws_size,
                              hipStream_t stream) {
    const float* x       = (const float*)d_in[0];
    const float* w_ih    = (const float*)d_in[1];
    const float* w_hh    = (const float*)d_in[2];
    const float* b_ih    = (const float*)d_in[3];
    const float* b_hh    = (const float*)d_in[4];
    const float* w_dense = (const float*)d_in[5];
    const float* b_dense = (const float*)d_in[6];
    float* out = (float*)d_out;

    // 2048 chains, one per 64-lane wave: 512 blocks x 256 threads
    // -> 2 blocks/CU, 8 waves/CU = 2 waves/SIMD (issue + latency overlap).
    lstm_fused<<<dim3(512), dim3(256), 0, stream>>>(x, w_ih, w_hh, b_ih, b_hh,
                                                    w_dense, b_dense, out);
}

// Round 5
// 695.660 us; speedup vs baseline: 1.5879x; 1.1407x over previous
//
#include <hip/hip_runtime.h>

#define T_LEN 2048
#define HID   25
#define LOG2E 1.4426950408889634f

__device__ __forceinline__ float fast_rcp(float x) { return __builtin_amdgcn_rcpf(x); }
__device__ __forceinline__ float fast_exp2(float x) { return __builtin_amdgcn_exp2f(x); }

// One chain per 64-lane wave. Lower lane u owns gate rows i_u,g_u; upper lane
// 32+u owns f_u,o_u (50 fp32 weights/lane). Uniform code on both halves; one
// shfl_xor(32) hands i*tanh(g) to the upper half which owns c,h.
// sigmoid/tanh in exp2 domain (weights pre-scaled by -log2e / +2log2e) ->
// v_exp_f32 + v_rcp_f32 only. Gate dots use two accumulators (k=0..11,
// k=12..24) to halve the fma dependency chain.
// y-output is batched: h history kept in padded LDS rows, reduced every 32
// steps (removes the per-step 5-shfl butterfly).

__global__ __launch_bounds__(256, 2) void lstm_fused(
    const float* __restrict__ x,        // [B, T, 1]
    const float* __restrict__ w_ih,     // [100, 1]
    const float* __restrict__ w_hh,     // [100, 25]
    const float* __restrict__ b_ih,     // [100]
    const float* __restrict__ b_hh,     // [100]
    const float* __restrict__ w_dense,  // [1, 25]
    const float* __restrict__ b_dense,  // [1]
    float* __restrict__ out)            // [B, T, 1]
{
    const int tid  = threadIdx.x;
    const int L    = tid & 63;           // lane in wave
    const int u    = L & 31;             // hidden-unit / t'-slot index
    const bool up  = L >= 32;            // upper half: f/o rows, owns c and h
    const int cl   = tid >> 6;           // wave (= chain) index in block, 0..3
    const int b    = blockIdx.x * 4 + cl;
    const bool act = u < HID;

    // Broadcast rows: [2cl+0]=scratch (lower-half junk publishes), [2cl+1]=real h.
    // 16B-aligned so the readback can use ds_read_b128.
    __shared__ __align__(16) float hbuf[8][32];
    // Per-wave h history for batched y: 32 steps x 33 floats (stride 33 keeps
    // the strided batch reads conflict-free: bank = t' + offset mod 32).
    __shared__ float hist[4][32][33];

    const int rowA = up ? (HID + u)     : u;              // f-row : i-row
    const int rowB = up ? (3 * HID + u) : (2 * HID + u);  // o-row : g-row
    const float sclA = -LOG2E;                            // sigmoid gates
    const float sclB = up ? -LOG2E : 2.f * LOG2E;         // o: sigmoid, g: tanh

    // ---- 50 recurrent fp32 weights per lane, pre-scaled into exp2 domain ----
    float wAv[HID], wBv[HID];
#pragma unroll
    for (int k = 0; k < HID; ++k) {
        wAv[k] = act ? sclA * w_hh[rowA * HID + k] : 0.f;
        wBv[k] = act ? sclB * w_hh[rowB * HID + k] : 0.f;
    }
    const float bA  = act ? sclA * (b_ih[rowA] + b_hh[rowA]) : 0.f;
    const float bB  = act ? sclB * (b_ih[rowB] + b_hh[rowB]) : 0.f;
    const float wxA = act ? sclA * w_ih[rowA] : 0.f;
    const float wxB = act ? sclB * w_ih[rowB] : 0.f;
    const float bd  = b_dense[0];
    // tB = fmaf(-tmul, sB, 1): tanh(g) on lower half, exactly 1.0 on upper
    const float tmul = up ? 0.f : 2.f;

    // dense weights for the batched y phase: lower half sums u'=0..12,
    // upper half sums u'=13..24 (13th term zero)
    const int u0 = up ? 13 : 0;
    float wdv[13];
#pragma unroll
    for (int i = 0; i < 13; ++i) wdv[i] = (u0 + i < HID) ? w_dense[u0 + i] : 0.f;

    // h0 = 0 in the broadcast row
    if (L < 32) hbuf[2 * cl + 1][L] = 0.f;

    // NOT __restrict__: these alias hbuf; C aliasing rules keep the
    // publish-before-readback order (no asm barriers needed).
    float* hwr = &hbuf[2 * cl + (up ? 1 : 0)][u];
    const float4* r4 = (const float4*)&hbuf[2 * cl + 1][0];
    const float* hbF = &hbuf[2 * cl + 1][0];

    const float4* __restrict__ xp = (const float4*)(x + (size_t)b * T_LEN);
    float* __restrict__ orow = out + (size_t)b * T_LEN;

    float hv[HID];
#pragma unroll
    for (int k = 0; k < HID; ++k) hv[k] = 0.f;

    float c = 0.f;        // real on upper half, bounded junk on lower
    float4 xcur = xp[0];

    for (int it = 0; it < T_LEN / 4; ++it) {
        const int nx = (it + 1 < T_LEN / 4) ? it + 1 : it;
        float4 xnext = xp[nx];  // issued ~1 iter (~4 steps) ahead of use
        float xs[4] = {xcur.x, xcur.y, xcur.z, xcur.w};

#pragma unroll
        for (int s = 0; s < 4; ++s) {
            const float xv = xs[s];
            const int t = 4 * it + s;

            // gate pre-activations, two accumulators per gate (chain 25->13)
            float aA0 = fmaf(xv, wxA, bA), aA1 = 0.f;
            float aB0 = fmaf(xv, wxB, bB), aB1 = 0.f;
#pragma unroll
            for (int k = 0; k < 12; ++k) {
                aA0 = fmaf(hv[k], wAv[k], aA0);
                aB0 = fmaf(hv[k], wBv[k], aB0);
            }
#pragma unroll
            for (int k = 12; k < HID; ++k) {
                aA1 = fmaf(hv[k], wAv[k], aA1);
                aB1 = fmaf(hv[k], wBv[k], aB1);
            }
            const float aA = aA0 + aA1;     // lower: i-preact, upper: f-preact
            const float aB = aB0 + aB1;     // lower: g-preact, upper: o-preact

            const float sA = fast_rcp(1.f + fast_exp2(aA));  // sig(i) / sig(f)
            const float sB = fast_rcp(1.f + fast_exp2(aB));  // g-aux  / sig(o)
            const float tB = fmaf(-tmul, sB, 1.f);           // tanh(g) / 1.0
            const float vv = sA * tB;                        // i*tanh(g) / sig(f)
            const float ov = __shfl_xor(vv, 32, 64);         // swap halves

            c = fmaf(vv, c, ov);             // upper: f*c + i*g   (lower: junk)
            const float tC = fmaf(-2.f, fast_rcp(1.f + fast_exp2(2.f * LOG2E * c)), 1.f);
            const float hn = sB * tC;        // upper: o*tanh(c)   (lower: junk)

            // publish h_t: broadcast row (unconditional; lower junk -> scratch
            // row) + history row for the batched y (gated to the 25 real lanes)
            *hwr = hn;
            if (up && act) hist[cl][t & 31][u] = hn;

            // read h_t back for the next step (broadcast b128s, conflict-free)
            {
                float4 a0 = r4[0], a1 = r4[1], a2 = r4[2];
                float4 a3 = r4[3], a4 = r4[4], a5 = r4[5];
                hv[0]  = a0.x; hv[1]  = a0.y; hv[2]  = a0.z; hv[3]  = a0.w;
                hv[4]  = a1.x; hv[5]  = a1.y; hv[6]  = a1.z; hv[7]  = a1.w;
                hv[8]  = a2.x; hv[9]  = a2.y; hv[10] = a2.z; hv[11] = a2.w;
                hv[12] = a3.x; hv[13] = a3.y; hv[14] = a3.z; hv[15] = a3.w;
                hv[16] = a4.x; hv[17] = a4.y; hv[18] = a4.z; hv[19] = a4.w;
                hv[20] = a5.x; hv[21] = a5.y; hv[22] = a5.z; hv[23] = a5.w;
                hv[24] = hbF[24];
            }

            // batched y: every 32 steps, lane L computes y[t0 + (L&31)] over
            // its half of the hidden units; shfl_xor(32) combines halves.
            if ((t & 31) == 31) {
                const float* hrow = &hist[cl][u][0];   // row for t' = t0 + u
                float ys = 0.f;
#pragma unroll
                for (int i = 0; i < 13; ++i)
                    ys = fmaf(hrow[u0 + i], wdv[i], ys);   // [25] slot reads junk*0
                ys += __shfl_xor(ys, 32, 64);
                if (!up) orow[(t & ~31) + u] = ys + bd;    // 128 B coalesced
            }
        }
        xcur = xnext;
    }
}

extern "C" void kernel_launch(void* const* d_in, const int* in_sizes, int n_in,
                              void* d_out, int out_size, void* d_ws, size_t ws_size,
                              hipStream_t stream) {
    const float* x       = (const float*)d_in[0];
    const float* w_ih    = (const float*)d_in[1];
    const float* w_hh    = (const float*)d_in[2];
    const float* b_ih    = (const float*)d_in[3];
    const float* b_hh    = (const float*)d_in[4];
    const float* w_dense = (const float*)d_in[5];
    const float* b_dense = (const float*)d_in[6];
    float* out = (float*)d_out;

    // 2048 chains, one per 64-lane wave: 512 blocks x 256 threads
    // -> 2 blocks/CU, 8 waves/CU = 2 waves/SIMD (issue + latency overlap).
    lstm_fused<<<dim3(512), dim3(256), 0, stream>>>(x, w_ih, w_hh, b_ih, b_hh,
                                                    w_dense, b_dense, out);
}